// Round 7
// baseline (433.710 us; speedup 1.0000x reference)
//
#include <hip/hip_runtime.h>
#include <hip/hip_bf16.h>
#include <stdint.h>

// VSN: B=16,T=256 -> NTOK=4096 tokens, V=64 vars, H=256 hidden.
#define NTOK 4096
#define NV 64
#define NH 256
#define LN_EPS 1e-5f

typedef __attribute__((ext_vector_type(8))) short short8;
typedef __attribute__((ext_vector_type(4))) float f32x4;
typedef __attribute__((ext_vector_type(4))) uint32_t u32x4;

__device__ __forceinline__ unsigned short f32_to_bf16(float f) {
    uint32_t u = __builtin_bit_cast(uint32_t, f);
    return (unsigned short)((u + 0x7FFFu + ((u >> 16) & 1u)) >> 16);  // RNE
}
__device__ __forceinline__ float fsigmoid(float z) { return 1.0f / (1.0f + __expf(-z)); }
__device__ __forceinline__ float felu(float z) { return z > 0.0f ? z : (__expf(z) - 1.0f); }
__device__ __forceinline__ uint32_t cvtpk_bf16(float lo, float hi) {
    uint32_t r;
    asm("v_cvt_pk_bf16_f32 %0, %1, %2" : "=v"(r) : "v"(lo), "v"(hi));
    return r;
}

// ---- Kernel A: W2 [v][h][o] f32 -> W2F fragment-major bf16 ----
// frag(v,ks,f,l)[j] = bf16(W2[v][ks*32+(l>>4)*8+j][f*16+(l&15)]); 16KB per (v,ks).
__global__ __launch_bounds__(128) void k_w2f(const float* __restrict__ W2,
                                             unsigned short* __restrict__ W2F) {
    __shared__ float tile[32][36];
    const int v  = blockIdx.x >> 6;
    const int t  = blockIdx.x & 63;
    const int ks = t & 7;
    const int o0 = (t >> 3) * 32;
    const int r  = threadIdx.x >> 2;
    const int c8 = (threadIdx.x & 3) * 8;
    const float* src = W2 + ((size_t)v * NH + ks * 32 + r) * NH + o0 + c8;
    *(float4*)&tile[r][c8]     = *(const float4*)src;
    *(float4*)&tile[r][c8 + 4] = *(const float4*)(src + 4);
    __syncthreads();
    const int fi = threadIdx.x >> 6;           // 0/1
    const int l  = threadIdx.x & 63;
    const int cc = l & 15, kg = l >> 4;
    const int f  = (o0 >> 4) + fi;
    u32x4 w;
#pragma unroll
    for (int p = 0; p < 4; ++p) {
        const float z0 = tile[kg * 8 + 2 * p][fi * 16 + cc];
        const float z1 = tile[kg * 8 + 2 * p + 1][fi * 16 + cc];
        w[p] = (uint32_t)f32_to_bf16(z0) | ((uint32_t)f32_to_bf16(z1) << 16);
    }
    *(u32x4*)(W2F + ((size_t)(((v * 8 + ks) * 16) + f) * 64 + l) * 8) = w;
}

// ---- Kernel A2: x [tok][v] -> xT [v][tok] ----
__global__ __launch_bounds__(256) void k_xt(const float* __restrict__ x,
                                            float* __restrict__ xT) {
    __shared__ float tile[64][65];
    const int t0 = blockIdx.x * 64;
    const int r = threadIdx.x >> 2, q = threadIdx.x & 3;
#pragma unroll
    for (int j = 0; j < 16; ++j)
        tile[r][q * 16 + j] = x[(size_t)(t0 + r) * NV + q * 16 + j];
    __syncthreads();
#pragma unroll
    for (int j = 0; j < 16; ++j)
        xT[(size_t)r * NTOK + t0 + q * 16 + j] = tile[q * 16 + j][r];
}

// ---- Kernel B: weight-network GRN + softmax -> wT[v][tok] ----
__global__ __launch_bounds__(256) void k_weights(
    const float* __restrict__ x,
    const float* __restrict__ nW1, const float* __restrict__ nb1,
    const float* __restrict__ nW2, const float* __restrict__ nb2,
    const float* __restrict__ nWg, const float* __restrict__ nbg,
    const float* __restrict__ ng,  const float* __restrict__ nbe,
    float* __restrict__ wT) {
    const int wv = threadIdx.x >> 6;
    const int lane = threadIdx.x & 63;
    const int tok = blockIdx.x * 4 + wv;
    const float xv = x[(size_t)tok * NV + lane];
    float acc1 = nb1[lane], accg = nbg[lane];
#pragma unroll 8
    for (int k = 0; k < 64; ++k) {
        const float xk = __shfl(xv, k);
        acc1 = fmaf(xk, nW1[k * 64 + lane], acc1);
        accg = fmaf(xk, nWg[k * 64 + lane], accg);
    }
    const float h  = felu(acc1);
    const float wg = fsigmoid(accg);
    float acc2 = nb2[lane];
#pragma unroll 8
    for (int k = 0; k < 64; ++k) {
        const float hk = __shfl(h, k);
        acc2 = fmaf(hk, nW2[k * 64 + lane], acc2);
    }
    const float pre = xv + wg * acc2;
    float s = pre;
#pragma unroll
    for (int m = 32; m >= 1; m >>= 1) s += __shfl_xor(s, m);
    const float mu = s * (1.0f / 64.0f);
    const float dd = pre - mu;
    float s2 = dd * dd;
#pragma unroll
    for (int m = 32; m >= 1; m >>= 1) s2 += __shfl_xor(s2, m);
    const float inv = rsqrtf(s2 * (1.0f / 64.0f) + LN_EPS);
    const float wln = dd * inv * ng[lane] + nbe[lane];
    float mx = wln;
#pragma unroll
    for (int m = 32; m >= 1; m >>= 1) mx = fmaxf(mx, __shfl_xor(mx, m));
    const float e = __expf(wln - mx);
    float se = e;
#pragma unroll
    for (int m = 32; m >= 1; m >>= 1) se += __shfl_xor(se, m);
    wT[(size_t)lane * NTOK + tok] = e / se;
}

// ---- Kernel C: reg-streamed B + LDS A-exchange fused GRN ----
// grid 512 (bid&7 = vgroup/XCD; bid>>3 = 64-tok tile). 512 thr = 8 waves =
// 2 tg(32tok) x 4 fq(64H). B-frags: global->reg dbuf (no LDS pipe, L2-resident
// 1MB/XCD). A-frags: each fq-wave computes 1/4 of its tg's A, exchanged via
// 2KB LDS dbuf (XOR-sloted, 2-way). acc[2][4]+wacc[2][4]+breg 2x16 ~ 126 VGPR
// -> 4 waves/SIMD. One barrier per ks (A swap; B drains under it).
__global__ __launch_bounds__(512, 4) void k_main(
    const char* __restrict__ W2F, const float* __restrict__ xT,
    const float* __restrict__ wT,
    const float* __restrict__ W1, const float* __restrict__ b1,
    const float* __restrict__ Wg, const float* __restrict__ bg,
    const float* __restrict__ Ws, const float* __restrict__ bs,
    const float* __restrict__ b2, const float* __restrict__ g1,
    const float* __restrict__ be1,
    float* __restrict__ partials,   // [8][NTOK][NH] or nullptr
    float* __restrict__ outacc) {
    __shared__ __align__(16) char sA[2][2][2048];  // [tg][buf][32tok x 4slot x 16B]
    __shared__ float sLN[2][32][4][2];             // [tg][tok][fq][ps,pq]

    const int tid = threadIdx.x;
    const int wid = tid >> 6, lane = tid & 63;
    const int c = lane & 15, kg = lane >> 4;
    const int tg = wid >> 2, fq = wid & 3;
    const int vg = blockIdx.x & 7, tt = blockIdx.x >> 3;
    const int t0 = tt * 64, vbase = vg * 8;
    const int tw = t0 + tg * 32;

    // A-writer lane geometry: token wtok, k-chunk (wkgrp, whalf), XOR slot
    const int wtok  = fq * 8 + (lane >> 3);
    const int wkgrp = (lane >> 1) & 3;
    const int whalf = lane & 1;
    const int kb    = wkgrp * 8 + whalf * 4;                    // k base (of 32)
    const int wbyte = wtok * 64 + ((wkgrp ^ ((wtok >> 1) & 3)) << 4) + whalf * 8;
    // A-reader byte offsets (per row-tile)
    const int rb0 = c * 64 + ((kg ^ ((c >> 1) & 3)) << 4);
    const int rb1 = 1024 + rb0;
    char* sAtg = &sA[tg][0][0];

    const f32x4 fzero = {0.f, 0.f, 0.f, 0.f};
    f32x4 acc[2][4], wacc[2][4];
    u32x4 bregA[4], bregB[4];
#pragma unroll
    for (int rt = 0; rt < 2; ++rt)
#pragma unroll
        for (int ff = 0; ff < 4; ++ff) wacc[rt][ff] = fzero;

    float xw_cur = xT[(size_t)vbase * NTOK + tw + wtok];
    float xw_nxt = 0.0f;

    // ---- prologue: B(v0,ks0) -> bregA; A(v0,ks0) -> buf0 ----
    {
        const char* bp = W2F + ((((size_t)vbase * 8 + 0) * 16 + fq * 4) << 10) + (lane << 4);
#pragma unroll
        for (int ff = 0; ff < 4; ++ff) bregA[ff] = *(const u32x4*)(bp + (ff << 10));
        const float4 w4 = *(const float4*)(W1 + (size_t)vbase * NH + kb);
        const float4 b4 = *(const float4*)(b1 + (size_t)vbase * NH + kb);
        uint2 pk;
        pk.x = cvtpk_bf16(felu(fmaf(xw_cur, w4.x, b4.x)), felu(fmaf(xw_cur, w4.y, b4.y)));
        pk.y = cvtpk_bf16(felu(fmaf(xw_cur, w4.z, b4.z)), felu(fmaf(xw_cur, w4.w, b4.w)));
        *(uint2*)(sAtg + wbyte) = pk;
    }
    __syncthreads();

// PHASE(KS, BCUR, BNXT, OCUR, ONXT): consume (v,KS), prefetch (vn,ksn)
#define PHASE(KS, BCUR, BNXT, OCUR, ONXT)                                          \
    do {                                                                           \
        const u32x4 a0raw = *(const u32x4*)(sAtg + (OCUR) + rb0);                  \
        const u32x4 a1raw = *(const u32x4*)(sAtg + (OCUR) + rb1);                  \
        if ((KS) == 0 && vi < 7)                                                   \
            xw_nxt = xT[(size_t)(v + 1) * NTOK + tw + wtok];                       \
        if (vi < 7 || (KS) < 7) {                                                  \
            const int vn = ((KS) < 7) ? v : v + 1;                                 \
            const int ksn = ((KS) + 1) & 7;                                        \
            const float xwp = ((KS) < 7) ? xw_cur : xw_nxt;                        \
            const char* bp = W2F +                                                 \
                ((((size_t)vn * 8 + ksn) * 16 + fq * 4) << 10) + (lane << 4);      \
            BNXT[0] = *(const u32x4*)(bp);                                         \
            BNXT[1] = *(const u32x4*)(bp + 1024);                                  \
            BNXT[2] = *(const u32x4*)(bp + 2048);                                  \
            BNXT[3] = *(const u32x4*)(bp + 3072);                                  \
            const float4 w4 = *(const float4*)(W1 + (size_t)vn * NH + ksn * 32 + kb); \
            const float4 b4 = *(const float4*)(b1 + (size_t)vn * NH + ksn * 32 + kb); \
            uint2 pk;                                                              \
            pk.x = cvtpk_bf16(felu(fmaf(xwp, w4.x, b4.x)),                         \
                              felu(fmaf(xwp, w4.y, b4.y)));                        \
            pk.y = cvtpk_bf16(felu(fmaf(xwp, w4.z, b4.z)),                         \
                              felu(fmaf(xwp, w4.w, b4.w)));                        \
            *(uint2*)(sAtg + (ONXT) + wbyte) = pk;                                 \
        }                                                                          \
        const short8 af0 = __builtin_bit_cast(short8, a0raw);                      \
        const short8 af1 = __builtin_bit_cast(short8, a1raw);                      \
        __builtin_amdgcn_s_setprio(1);                                             \
        _Pragma("unroll") for (int ff = 0; ff < 4; ++ff) {                         \
            const short8 bf = __builtin_bit_cast(short8, BCUR[ff]);                \
            acc[0][ff] = __builtin_amdgcn_mfma_f32_16x16x32_bf16(af0, bf,          \
                                                                 acc[0][ff], 0, 0, 0); \
            acc[1][ff] = __builtin_amdgcn_mfma_f32_16x16x32_bf16(af1, bf,          \
                                                                 acc[1][ff], 0, 0, 0); \
        }                                                                          \
        __builtin_amdgcn_s_setprio(0);                                             \
        __syncthreads();                                                           \
    } while (0)

#pragma unroll 1
    for (int vi = 0; vi < 8; ++vi) {
        const int v = vbase + vi;
#pragma unroll
        for (int rt = 0; rt < 2; ++rt)
#pragma unroll
            for (int ff = 0; ff < 4; ++ff) acc[rt][ff] = fzero;

#pragma unroll 1
        for (int kss = 0; kss < 8; kss += 2) {
            const int ks0 = kss;                 // even
            switch (ks0) {                       // compile-time KS for guards
                case 0: PHASE(0, bregA, bregB, 0, 2048); PHASE(1, bregB, bregA, 2048, 0); break;
                case 2: PHASE(2, bregA, bregB, 0, 2048); PHASE(3, bregB, bregA, 2048, 0); break;
                case 4: PHASE(4, bregA, bregB, 0, 2048); PHASE(5, bregB, bregA, 2048, 0); break;
                default: PHASE(6, bregA, bregB, 0, 2048); PHASE(7, bregB, bregA, 2048, 0); break;
            }
        }
        xw_cur = xw_nxt;

        // ---- epilogue: gate/skip/sigmoid, cross-fq LN, weighted accumulate ----
        const float4 xr40 = *(const float4*)&xT[(size_t)v * NTOK + tw + kg * 4];
        const float4 xr41 = *(const float4*)&xT[(size_t)v * NTOK + tw + 16 + kg * 4];
        const float4 wr40 = *(const float4*)&wT[(size_t)v * NTOK + tw + kg * 4];
        const float4 wr41 = *(const float4*)&wT[(size_t)v * NTOK + tw + 16 + kg * 4];
        const float xr[2][4] = {{xr40.x, xr40.y, xr40.z, xr40.w},
                                {xr41.x, xr41.y, xr41.z, xr41.w}};
        const float wv_[2][4] = {{wr40.x, wr40.y, wr40.z, wr40.w},
                                 {wr41.x, wr41.y, wr41.z, wr41.w}};
        float ps[2][4] = {}, pq[2][4] = {};
        const size_t vro = (size_t)v * NH + fq * 64 + c;
#pragma unroll
        for (int ff = 0; ff < 4; ++ff) {
            const float WgL = -1.44269504f * Wg[vro + ff * 16];
            const float bgL = -1.44269504f * bg[vro + ff * 16];
            const float Ws_ = Ws[vro + ff * 16], bs_ = bs[vro + ff * 16];
            const float b2_ = b2[vro + ff * 16];
#pragma unroll
            for (int rt = 0; rt < 2; ++rt)
#pragma unroll
                for (int r = 0; r < 4; ++r) {
                    const float e = exp2f(fmaf(xr[rt][r], WgL, bgL));
                    const float sig = __builtin_amdgcn_rcpf(1.0f + e);
                    const float y = fmaf(xr[rt][r], Ws_, bs_) +
                                    sig * (acc[rt][ff][r] + b2_);
                    acc[rt][ff][r] = y;
                    ps[rt][r] += y;
                    pq[rt][r] = fmaf(y, y, pq[rt][r]);
                }
        }
#pragma unroll
        for (int m = 1; m <= 8; m <<= 1)
#pragma unroll
            for (int rt = 0; rt < 2; ++rt)
#pragma unroll
                for (int r = 0; r < 4; ++r) {
                    ps[rt][r] += __shfl_xor(ps[rt][r], m);
                    pq[rt][r] += __shfl_xor(pq[rt][r], m);
                }
        if (c == 0) {
#pragma unroll
            for (int rt = 0; rt < 2; ++rt)
#pragma unroll
                for (int r = 0; r < 4; ++r)
                    *(float2*)&sLN[tg][rt * 16 + kg * 4 + r][fq][0] =
                        float2{ps[rt][r], pq[rt][r]};
        }
        __syncthreads();
        float mu[2][4], wiv[2][4];
#pragma unroll
        for (int rt = 0; rt < 2; ++rt)
#pragma unroll
            for (int r = 0; r < 4; ++r) {
                const float4 q01 = *(const float4*)&sLN[tg][rt * 16 + kg * 4 + r][0][0];
                const float4 q23 = *(const float4*)&sLN[tg][rt * 16 + kg * 4 + r][2][0];
                const float S = q01.x + q01.z + q23.x + q23.z;
                const float Q = q01.y + q01.w + q23.y + q23.w;
                mu[rt][r] = S * (1.0f / 256.0f);
                const float vr = fmaf(-mu[rt][r], mu[rt][r], Q * (1.0f / 256.0f));
                wiv[rt][r] = wv_[rt][r] * rsqrtf(vr + LN_EPS);
            }
#pragma unroll
        for (int ff = 0; ff < 4; ++ff) {
            const float g1_ = g1[vro + ff * 16], be_ = be1[vro + ff * 16];
#pragma unroll
            for (int rt = 0; rt < 2; ++rt)
#pragma unroll
                for (int r = 0; r < 4; ++r)
                    wacc[rt][ff][r] = fmaf(wiv[rt][r] * (acc[rt][ff][r] - mu[rt][r]),
                                           g1_, fmaf(wv_[rt][r], be_, wacc[rt][ff][r]));
        }
        __syncthreads();   // sLN reads done before next var's writes
    }
#undef PHASE

    // ---- write per-vgroup partials (this wave's 64-H quarter) ----
    if (partials) {
        float* P = partials + (size_t)vg * NTOK * NH;
#pragma unroll
        for (int rt = 0; rt < 2; ++rt)
#pragma unroll
            for (int r = 0; r < 4; ++r) {
                float* rowp = P + (size_t)(tw + rt * 16 + kg * 4 + r) * NH + fq * 64 + c;
#pragma unroll
                for (int ff = 0; ff < 4; ++ff) rowp[ff * 16] = wacc[rt][ff][r];
            }
    } else {
#pragma unroll
        for (int rt = 0; rt < 2; ++rt)
#pragma unroll
            for (int r = 0; r < 4; ++r) {
                float* rowp = outacc + (size_t)(tw + rt * 16 + kg * 4 + r) * NH + fq * 64 + c;
#pragma unroll
                for (int ff = 0; ff < 4; ++ff) atomicAdd(&rowp[ff * 16], wacc[rt][ff][r]);
            }
    }
}

// ---- Kernel D: sum the 8 vgroup partials ----
__global__ __launch_bounds__(256) void k_reduce(const float* __restrict__ P,
                                                float* __restrict__ out) {
    const size_t i = ((size_t)blockIdx.x * 256 + threadIdx.x);
    const f32x4* P4 = (const f32x4*)P;
    f32x4 s = P4[i];
#pragma unroll
    for (int sl = 1; sl < 8; ++sl) s += P4[(size_t)sl * (NTOK * NH / 4) + i];
    ((f32x4*)out)[i] = s;
}

extern "C" void kernel_launch(void* const* d_in, const int* in_sizes, int n_in,
                              void* d_out, int out_size, void* d_ws, size_t ws_size,
                              hipStream_t stream) {
    const float* x   = (const float*)d_in[0];
    const float* W1  = (const float*)d_in[1];
    const float* b1  = (const float*)d_in[2];
    const float* W2  = (const float*)d_in[3];
    const float* b2  = (const float*)d_in[4];
    const float* Wg  = (const float*)d_in[5];
    const float* bg  = (const float*)d_in[6];
    const float* Ws  = (const float*)d_in[7];
    const float* bs  = (const float*)d_in[8];
    const float* g1  = (const float*)d_in[9];
    const float* be1 = (const float*)d_in[10];
    const float* nW1 = (const float*)d_in[11];
    const float* nb1 = (const float*)d_in[12];
    const float* nW2 = (const float*)d_in[13];
    const float* nb2 = (const float*)d_in[14];
    const float* nWg = (const float*)d_in[15];
    const float* nbg = (const float*)d_in[16];
    const float* ng  = (const float*)d_in[17];
    const float* nbe = (const float*)d_in[18];
    float* out = (float*)d_out;

    // ws: [0,1M) wT | [1,2M) xT | [2,10M) W2F | [10M,42M) partials
    char* ws = (char*)d_ws;
    float* ws_wT  = (float*)ws;
    float* ws_xT  = (float*)(ws + (1 << 20));
    unsigned short* ws_W2F = (unsigned short*)(ws + (2 << 20));
    const size_t part_off = (size_t)10 << 20;
    const size_t part_bytes = (size_t)8 * NTOK * NH * 4;
    const bool use_part = ws_size >= part_off + part_bytes;
    float* ws_part = use_part ? (float*)(ws + part_off) : nullptr;

    k_w2f<<<dim3(64 * 64), dim3(128), 0, stream>>>(W2, ws_W2F);
    k_xt<<<dim3(NTOK / 64), dim3(256), 0, stream>>>(x, ws_xT);
    k_weights<<<dim3(NTOK / 4), dim3(256), 0, stream>>>(x, nW1, nb1, nW2, nb2,
                                                        nWg, nbg, ng, nbe, ws_wT);
    if (!use_part) hipMemsetAsync(d_out, 0, (size_t)out_size * 4, stream);
    k_main<<<dim3(512), dim3(512), 0, stream>>>((const char*)ws_W2F, ws_xT, ws_wT,
                                                W1, b1, Wg, bg, Ws, bs, b2, g1, be1,
                                                ws_part, out);
    if (use_part)
        k_reduce<<<dim3(NTOK * NH / 4 / 256), dim3(256), 0, stream>>>(ws_part, out);
}

// Round 8
// 161.993 us; speedup vs baseline: 2.6773x; 2.6773x over previous
//
#include <hip/hip_runtime.h>
#include <hip/hip_bf16.h>
#include <stdint.h>

// VSN: B=16,T=256 -> NTOK=4096 tokens, V=64 vars, H=256 hidden.
#define NTOK 4096
#define NV 64
#define NH 256
#define LN_EPS 1e-5f

typedef __attribute__((ext_vector_type(8))) short short8;
typedef __attribute__((ext_vector_type(4))) float f32x4;
typedef __attribute__((ext_vector_type(4))) uint32_t u32x4;

__device__ __forceinline__ unsigned short f32_to_bf16(float f) {
    uint32_t u = __builtin_bit_cast(uint32_t, f);
    return (unsigned short)((u + 0x7FFFu + ((u >> 16) & 1u)) >> 16);  // RNE
}
__device__ __forceinline__ float fsigmoid(float z) { return 1.0f / (1.0f + __expf(-z)); }
__device__ __forceinline__ float felu(float z) { return z > 0.0f ? z : (__expf(z) - 1.0f); }
__device__ __forceinline__ uint32_t cvtpk_bf16(float lo, float hi) {
    uint32_t r;
    asm("v_cvt_pk_bf16_f32 %0, %1, %2" : "=v"(r) : "v"(lo), "v"(hi));
    return r;
}
__device__ __forceinline__ void gload16(const void* g, void* l) {
    __builtin_amdgcn_global_load_lds(
        (const __attribute__((address_space(1))) uint32_t*)g,
        (__attribute__((address_space(3))) uint32_t*)l, 16, 0, 0);
}

// ---- Kernel A: W2 [v][h][o] f32 -> W2F fragment-major bf16 ----
// frag(v,ks,f,l)[j] = bf16(W2[v][ks*32+(l>>4)*8+j][f*16+(l&15)]); 16KB per (v,ks).
__global__ __launch_bounds__(128) void k_w2f(const float* __restrict__ W2,
                                             unsigned short* __restrict__ W2F) {
    __shared__ float tile[32][36];
    const int v  = blockIdx.x >> 6;
    const int t  = blockIdx.x & 63;
    const int ks = t & 7;
    const int o0 = (t >> 3) * 32;
    const int r  = threadIdx.x >> 2;
    const int c8 = (threadIdx.x & 3) * 8;
    const float* src = W2 + ((size_t)v * NH + ks * 32 + r) * NH + o0 + c8;
    *(float4*)&tile[r][c8]     = *(const float4*)src;
    *(float4*)&tile[r][c8 + 4] = *(const float4*)(src + 4);
    __syncthreads();
    const int fi = threadIdx.x >> 6;           // 0/1
    const int l  = threadIdx.x & 63;
    const int cc = l & 15, kg = l >> 4;
    const int f  = (o0 >> 4) + fi;
    u32x4 w;
#pragma unroll
    for (int p = 0; p < 4; ++p) {
        const float z0 = tile[kg * 8 + 2 * p][fi * 16 + cc];
        const float z1 = tile[kg * 8 + 2 * p + 1][fi * 16 + cc];
        w[p] = (uint32_t)f32_to_bf16(z0) | ((uint32_t)f32_to_bf16(z1) << 16);
    }
    *(u32x4*)(W2F + ((size_t)(((v * 8 + ks) * 16) + f) * 64 + l) * 8) = w;
}

// ---- Kernel A2: x [tok][v] -> xT [v][tok] ----
__global__ __launch_bounds__(256) void k_xt(const float* __restrict__ x,
                                            float* __restrict__ xT) {
    __shared__ float tile[64][65];
    const int t0 = blockIdx.x * 64;
    const int r = threadIdx.x >> 2, q = threadIdx.x & 3;
#pragma unroll
    for (int j = 0; j < 16; ++j)
        tile[r][q * 16 + j] = x[(size_t)(t0 + r) * NV + q * 16 + j];
    __syncthreads();
#pragma unroll
    for (int j = 0; j < 16; ++j)
        xT[(size_t)r * NTOK + t0 + q * 16 + j] = tile[q * 16 + j][r];
}

// ---- Kernel B: weight-network GRN + softmax -> wT[v][tok] ----
__global__ __launch_bounds__(256) void k_weights(
    const float* __restrict__ x,
    const float* __restrict__ nW1, const float* __restrict__ nb1,
    const float* __restrict__ nW2, const float* __restrict__ nb2,
    const float* __restrict__ nWg, const float* __restrict__ nbg,
    const float* __restrict__ ng,  const float* __restrict__ nbe,
    float* __restrict__ wT) {
    const int wv = threadIdx.x >> 6;
    const int lane = threadIdx.x & 63;
    const int tok = blockIdx.x * 4 + wv;
    const float xv = x[(size_t)tok * NV + lane];
    float acc1 = nb1[lane], accg = nbg[lane];
#pragma unroll 8
    for (int k = 0; k < 64; ++k) {
        const float xk = __shfl(xv, k);
        acc1 = fmaf(xk, nW1[k * 64 + lane], acc1);
        accg = fmaf(xk, nWg[k * 64 + lane], accg);
    }
    const float h  = felu(acc1);
    const float wg = fsigmoid(accg);
    float acc2 = nb2[lane];
#pragma unroll 8
    for (int k = 0; k < 64; ++k) {
        const float hk = __shfl(h, k);
        acc2 = fmaf(hk, nW2[k * 64 + lane], acc2);
    }
    const float pre = xv + wg * acc2;
    float s = pre;
#pragma unroll
    for (int m = 32; m >= 1; m >>= 1) s += __shfl_xor(s, m);
    const float mu = s * (1.0f / 64.0f);
    const float dd = pre - mu;
    float s2 = dd * dd;
#pragma unroll
    for (int m = 32; m >= 1; m >>= 1) s2 += __shfl_xor(s2, m);
    const float inv = rsqrtf(s2 * (1.0f / 64.0f) + LN_EPS);
    const float wln = dd * inv * ng[lane] + nbe[lane];
    float mx = wln;
#pragma unroll
    for (int m = 32; m >= 1; m >>= 1) mx = fmaxf(mx, __shfl_xor(mx, m));
    const float e = __expf(wln - mx);
    float se = e;
#pragma unroll
    for (int m = 32; m >= 1; m >>= 1) se += __shfl_xor(se, m);
    wT[(size_t)lane * NTOK + tok] = e / se;
}

// ---- Kernel C: M=32xN=64 waves, A-dedup LDS exchange, atomic combine ----
// grid 1024 (bid&7 = vgroup/XCD; bid>>3 = 32-tok tile). 256 thr = 4 waves,
// wave fq owns cols [fq*64, fq*64+64). acc+wacc = 64 VGPR -> 4 waves/SIMD,
// 4 blocks/CU (LDS 37.9KB). B panel: linear frag-major LDS copy (contiguous
// 1KB frag reads, conflict-free). A: generated once (each wave its k-quarter),
// exchanged via stride-80 LDS dbuf under the per-ks barrier.
__global__ __launch_bounds__(256, 4) void k_main(
    const char* __restrict__ W2F, const float* __restrict__ xT,
    const float* __restrict__ wT,
    const float* __restrict__ W1, const float* __restrict__ b1,
    const float* __restrict__ Wg, const float* __restrict__ bg,
    const float* __restrict__ Ws, const float* __restrict__ bs,
    const float* __restrict__ b2, const float* __restrict__ g1,
    const float* __restrict__ be1,
    float* __restrict__ out) {
    __shared__ __align__(16) char sB[2][16384];  // B panel dbuf (frag-major)
    __shared__ __align__(16) char sA[2][2560];   // A dbuf: 32 tok x 80B
                                                 // sA[1] doubles as LN scratch

    const int tid = threadIdx.x;
    const int wid = tid >> 6, lane = tid & 63;
    const int c = lane & 15, kg = lane >> 4;
    const int fq = wid;
    const int vg = blockIdx.x & 7, tt = blockIdx.x >> 3;
    const int t0 = tt * 32, vbase = vg * 8;

    // A-writer: lane -> token lane>>1, k-slice fq*8 + (lane&1)*4 + 0..3
    const int wtok = lane >> 1, whalf = lane & 1;
    const int awbyte = wtok * 80 + fq * 16 + whalf * 8;
    const int wkb = fq * 8 + whalf * 4;
    // A-reader byte offsets (row-tile 0/1)
    const int arb0 = c * 80 + kg * 16;
    const int arb1 = (16 + c) * 80 + kg * 16;
    // B-frag read base: frag f = fq*4+ff at f*1024 + lane*16 (contiguous)
    const int brb = (fq * 4) * 1024 + lane * 16;

    float xw = xT[(size_t)vbase * NTOK + t0 + wtok];
    float xw_nxt = 0.0f;

    // ---- prologue: stage B(v0,ks0) + gen A(v0,ks0) into buf0 ----
    {
        const char* src = W2F + (size_t)vbase * 131072;
#pragma unroll
        for (int q = 0; q < 4; ++q) {
            const int ch = tid + q * 256;
            gload16(src + ch * 16, sB[0] + ch * 16);
        }
        const float4 w4 = *(const float4*)(W1 + (size_t)vbase * NH + wkb);
        const float4 b4 = *(const float4*)(b1 + (size_t)vbase * NH + wkb);
        uint2 pk;
        pk.x = cvtpk_bf16(felu(fmaf(xw, w4.x, b4.x)), felu(fmaf(xw, w4.y, b4.y)));
        pk.y = cvtpk_bf16(felu(fmaf(xw, w4.z, b4.z)), felu(fmaf(xw, w4.w, b4.w)));
        *(uint2*)(sA[0] + awbyte) = pk;
    }
    __syncthreads();

    const f32x4 fzero = {0.f, 0.f, 0.f, 0.f};
    f32x4 wacc[2][4];
#pragma unroll
    for (int rt = 0; rt < 2; ++rt)
#pragma unroll
        for (int ff = 0; ff < 4; ++ff) wacc[rt][ff] = fzero;

#pragma unroll 1
    for (int vi = 0; vi < 8; ++vi) {
        const int v = vbase + vi;
        f32x4 acc[2][4];
#pragma unroll
        for (int rt = 0; rt < 2; ++rt)
#pragma unroll
            for (int ff = 0; ff < 4; ++ff) acc[rt][ff] = fzero;

#pragma unroll 1
        for (int ks = 0; ks < 8; ++ks) {
            const int cur = ks & 1, nxt = cur ^ 1;
            // current-phase fragments
            const u32x4 a0raw = *(const u32x4*)(sA[cur] + arb0);
            const u32x4 a1raw = *(const u32x4*)(sA[cur] + arb1);
            u32x4 bfr[4];
#pragma unroll
            for (int ff = 0; ff < 4; ++ff)
                bfr[ff] = *(const u32x4*)(sB[cur] + brb + (ff << 10));
            if (ks == 0 && vi < 7)
                xw_nxt = xT[(size_t)(v + 1) * NTOK + t0 + wtok];
            // stage next phase (B panel + A slice)
            if (ks < 7 || vi < 7) {
                const int vn = (ks < 7) ? v : v + 1;
                const int ksn = (ks + 1) & 7;
                const float xwp = (ks < 7) ? xw : xw_nxt;
                const char* src = W2F + ((size_t)vn * 8 + ksn) * 16384;
#pragma unroll
                for (int q = 0; q < 4; ++q) {
                    const int ch = tid + q * 256;
                    gload16(src + ch * 16, sB[nxt] + ch * 16);
                }
                const float4 w4 = *(const float4*)(W1 + (size_t)vn * NH + ksn * 32 + wkb);
                const float4 b4 = *(const float4*)(b1 + (size_t)vn * NH + ksn * 32 + wkb);
                uint2 pk;
                pk.x = cvtpk_bf16(felu(fmaf(xwp, w4.x, b4.x)),
                                  felu(fmaf(xwp, w4.y, b4.y)));
                pk.y = cvtpk_bf16(felu(fmaf(xwp, w4.z, b4.z)),
                                  felu(fmaf(xwp, w4.w, b4.w)));
                *(uint2*)(sA[nxt] + awbyte) = pk;
            }
            // MFMA: 2 row-tiles x 4 col-frags
            const short8 af0 = __builtin_bit_cast(short8, a0raw);
            const short8 af1 = __builtin_bit_cast(short8, a1raw);
            __builtin_amdgcn_s_setprio(1);
#pragma unroll
            for (int ff = 0; ff < 4; ++ff) {
                const short8 bf = __builtin_bit_cast(short8, bfr[ff]);
                acc[0][ff] = __builtin_amdgcn_mfma_f32_16x16x32_bf16(af0, bf, acc[0][ff], 0, 0, 0);
                acc[1][ff] = __builtin_amdgcn_mfma_f32_16x16x32_bf16(af1, bf, acc[1][ff], 0, 0, 0);
            }
            __builtin_amdgcn_s_setprio(0);
            __syncthreads();
        }
        xw = xw_nxt;

        // ---- epilogue: gate/skip/sigmoid, cross-wave LN, weighted accumulate ----
        const float4 xr40 = *(const float4*)&xT[(size_t)v * NTOK + t0 + kg * 4];
        const float4 xr41 = *(const float4*)&xT[(size_t)v * NTOK + t0 + 16 + kg * 4];
        const float4 wr40 = *(const float4*)&wT[(size_t)v * NTOK + t0 + kg * 4];
        const float4 wr41 = *(const float4*)&wT[(size_t)v * NTOK + t0 + 16 + kg * 4];
        const float xr[2][4] = {{xr40.x, xr40.y, xr40.z, xr40.w},
                                {xr41.x, xr41.y, xr41.z, xr41.w}};
        const float wv_[2][4] = {{wr40.x, wr40.y, wr40.z, wr40.w},
                                 {wr41.x, wr41.y, wr41.z, wr41.w}};
        float ps[2][4] = {}, pq[2][4] = {};
        const size_t vro = (size_t)v * NH + fq * 64 + c;
#pragma unroll
        for (int ff = 0; ff < 4; ++ff) {
            const float Wg_ = Wg[vro + ff * 16], bg_ = bg[vro + ff * 16];
            const float Ws_ = Ws[vro + ff * 16], bs_ = bs[vro + ff * 16];
            const float b2_ = b2[vro + ff * 16];
#pragma unroll
            for (int rt = 0; rt < 2; ++rt)
#pragma unroll
                for (int r = 0; r < 4; ++r) {
                    const float z = fmaf(xr[rt][r], Wg_, bg_);
                    const float e = exp2f(z * -1.44269504f);
                    const float sig = __builtin_amdgcn_rcpf(1.0f + e);
                    const float y = fmaf(xr[rt][r], Ws_, bs_) +
                                    sig * (acc[rt][ff][r] + b2_);
                    acc[rt][ff][r] = y;
                    ps[rt][r] += y;
                    pq[rt][r] = fmaf(y, y, pq[rt][r]);
                }
        }
#pragma unroll
        for (int m = 1; m <= 8; m <<= 1)
#pragma unroll
            for (int rt = 0; rt < 2; ++rt)
#pragma unroll
                for (int r = 0; r < 4; ++r) {
                    ps[rt][r] += __shfl_xor(ps[rt][r], m);
                    pq[rt][r] += __shfl_xor(pq[rt][r], m);
                }
        // partial (ps,pq) per (token, fq) -> scratch (sA[1] is dead here)
        char* scratch = sA[1];
        if (c == 0) {
#pragma unroll
            for (int rt = 0; rt < 2; ++rt)
#pragma unroll
                for (int r = 0; r < 4; ++r) {
                    const int tok = rt * 16 + kg * 4 + r;
                    *(float2*)(scratch + tok * 32 + fq * 8) = float2{ps[rt][r], pq[rt][r]};
                }
        }
        __syncthreads();
        float mu[2][4], wiv[2][4];
#pragma unroll
        for (int rt = 0; rt < 2; ++rt)
#pragma unroll
            for (int r = 0; r < 4; ++r) {
                const int tok = rt * 16 + kg * 4 + r;
                const f32x4 s01 = *(const f32x4*)(scratch + tok * 32);
                const f32x4 s23 = *(const f32x4*)(scratch + tok * 32 + 16);
                const float S = s01[0] + s01[2] + s23[0] + s23[2];
                const float Q = s01[1] + s01[3] + s23[1] + s23[3];
                mu[rt][r] = S * (1.0f / 256.0f);
                const float vr = fmaf(-mu[rt][r], mu[rt][r], Q * (1.0f / 256.0f));
                wiv[rt][r] = wv_[rt][r] * rsqrtf(vr + LN_EPS);
            }
#pragma unroll
        for (int ff = 0; ff < 4; ++ff) {
            const float g1_ = g1[vro + ff * 16], be_ = be1[vro + ff * 16];
#pragma unroll
            for (int rt = 0; rt < 2; ++rt)
#pragma unroll
                for (int r = 0; r < 4; ++r)
                    wacc[rt][ff][r] = fmaf(wiv[rt][r] * (acc[rt][ff][r] - mu[rt][r]),
                                           g1_, fmaf(wv_[rt][r], be_, wacc[rt][ff][r]));
        }
        __syncthreads();   // scratch reads done before next var's sA[1] writes
    }

    // ---- combine across vgroups: atomicAdd into out[t][h] ----
#pragma unroll
    for (int rt = 0; rt < 2; ++rt)
#pragma unroll
        for (int r = 0; r < 4; ++r) {
            float* rowp = out + (size_t)(t0 + rt * 16 + kg * 4 + r) * NH + fq * 64 + c;
#pragma unroll
            for (int ff = 0; ff < 4; ++ff)
                atomicAdd(&rowp[ff * 16], wacc[rt][ff][r]);
        }
}

extern "C" void kernel_launch(void* const* d_in, const int* in_sizes, int n_in,
                              void* d_out, int out_size, void* d_ws, size_t ws_size,
                              hipStream_t stream) {
    const float* x   = (const float*)d_in[0];
    const float* W1  = (const float*)d_in[1];
    const float* b1  = (const float*)d_in[2];
    const float* W2  = (const float*)d_in[3];
    const float* b2  = (const float*)d_in[4];
    const float* Wg  = (const float*)d_in[5];
    const float* bg  = (const float*)d_in[6];
    const float* Ws  = (const float*)d_in[7];
    const float* bs  = (const float*)d_in[8];
    const float* g1  = (const float*)d_in[9];
    const float* be1 = (const float*)d_in[10];
    const float* nW1 = (const float*)d_in[11];
    const float* nb1 = (const float*)d_in[12];
    const float* nW2 = (const float*)d_in[13];
    const float* nb2 = (const float*)d_in[14];
    const float* nWg = (const float*)d_in[15];
    const float* nbg = (const float*)d_in[16];
    const float* ng  = (const float*)d_in[17];
    const float* nbe = (const float*)d_in[18];
    float* out = (float*)d_out;

    // ws: [0,1M) wT | [1,2M) xT | [2,10M) W2F
    char* ws = (char*)d_ws;
    float* ws_wT  = (float*)ws;
    float* ws_xT  = (float*)(ws + (1 << 20));
    unsigned short* ws_W2F = (unsigned short*)(ws + (2 << 20));

    k_w2f<<<dim3(64 * 64), dim3(128), 0, stream>>>(W2, ws_W2F);
    k_xt<<<dim3(NTOK / 64), dim3(256), 0, stream>>>(x, ws_xT);
    k_weights<<<dim3(NTOK / 4), dim3(256), 0, stream>>>(x, nW1, nb1, nW2, nb2,
                                                        nWg, nbg, ng, nbe, ws_wT);
    hipMemsetAsync(d_out, 0, (size_t)out_size * sizeof(float), stream);
    k_main<<<dim3(1024), dim3(256), 0, stream>>>((const char*)ws_W2F, ws_xT, ws_wT,
                                                 W1, b1, Wg, bg, Ws, bs, b2, g1, be1,
                                                 out);
}

// Round 9
// 141.298 us; speedup vs baseline: 3.0695x; 1.1465x over previous
//
#include <hip/hip_runtime.h>
#include <hip/hip_bf16.h>
#include <stdint.h>

// VSN: B=16,T=256 -> NTOK=4096 tokens, V=64 vars, H=256 hidden.
#define NTOK 4096
#define NV 64
#define NH 256
#define LN_EPS 1e-5f

typedef __attribute__((ext_vector_type(8))) short short8;
typedef __attribute__((ext_vector_type(4))) float f32x4;
typedef __attribute__((ext_vector_type(4))) uint32_t u32x4;

__device__ __forceinline__ unsigned short f32_to_bf16(float f) {
    uint32_t u = __builtin_bit_cast(uint32_t, f);
    return (unsigned short)((u + 0x7FFFu + ((u >> 16) & 1u)) >> 16);  // RNE
}
__device__ __forceinline__ float fsigmoid(float z) { return 1.0f / (1.0f + __expf(-z)); }
__device__ __forceinline__ float felu(float z) { return z > 0.0f ? z : (__expf(z) - 1.0f); }
// pack two f32 -> bf16x2 (round-half-up) in 3 ops: 2 adds + v_perm
__device__ __forceinline__ uint32_t pack_bf16x2(float ze, float zo) {
    const uint32_t ue = __builtin_bit_cast(uint32_t, ze) + 0x8000u;
    const uint32_t uo = __builtin_bit_cast(uint32_t, zo) + 0x8000u;
    return __builtin_amdgcn_perm(uo, ue, 0x07060302u);  // (hi16(uo)<<16)|hi16(ue)
}
__device__ __forceinline__ void gload16(const void* g, void* l) {
    __builtin_amdgcn_global_load_lds(
        (const __attribute__((address_space(1))) uint32_t*)g,
        (__attribute__((address_space(3))) uint32_t*)l, 16, 0, 0);
}

// ---------------- Kernel A: W2 [v][h][o] f32 -> W2T [v][o][h] bf16 ----------------
__global__ __launch_bounds__(256) void k_w2t(const float* __restrict__ W2,
                                             unsigned short* __restrict__ W2T) {
    __shared__ float tile[32][33];
    const int v  = blockIdx.x >> 6;
    const int t  = blockIdx.x & 63;
    const int h0 = (t & 7) * 32;
    const int o0 = (t >> 3) * 32;
    const int r  = threadIdx.x >> 3;
    const int c4 = (threadIdx.x & 7) * 4;
    const float4 d = *(const float4*)(W2 + ((size_t)v * NH + h0 + r) * NH + o0 + c4);
    tile[r][c4 + 0] = d.x; tile[r][c4 + 1] = d.y;
    tile[r][c4 + 2] = d.z; tile[r][c4 + 3] = d.w;
    __syncthreads();
    ushort4 o;
    o.x = f32_to_bf16(tile[c4 + 0][r]);
    o.y = f32_to_bf16(tile[c4 + 1][r]);
    o.z = f32_to_bf16(tile[c4 + 2][r]);
    o.w = f32_to_bf16(tile[c4 + 3][r]);
    *(ushort4*)(W2T + ((size_t)v * NH + o0 + r) * NH + h0 + c4) = o;
}

// ---------------- Kernel B: weight-network GRN + softmax -> weights[tok][v] -------
__global__ __launch_bounds__(256) void k_weights(
    const float* __restrict__ x,
    const float* __restrict__ nW1, const float* __restrict__ nb1,
    const float* __restrict__ nW2, const float* __restrict__ nb2,
    const float* __restrict__ nWg, const float* __restrict__ nbg,
    const float* __restrict__ ng,  const float* __restrict__ nbe,
    float* __restrict__ wout_buf) {
    const int wv = threadIdx.x >> 6;
    const int lane = threadIdx.x & 63;
    const int tok = blockIdx.x * 4 + wv;
    const float xv = x[(size_t)tok * NV + lane];
    float acc1 = nb1[lane], accg = nbg[lane];
#pragma unroll 8
    for (int k = 0; k < 64; ++k) {
        const float xk = __shfl(xv, k);
        acc1 = fmaf(xk, nW1[k * 64 + lane], acc1);
        accg = fmaf(xk, nWg[k * 64 + lane], accg);
    }
    const float h  = felu(acc1);
    const float wg = fsigmoid(accg);
    float acc2 = nb2[lane];
#pragma unroll 8
    for (int k = 0; k < 64; ++k) {
        const float hk = __shfl(h, k);
        acc2 = fmaf(hk, nW2[k * 64 + lane], acc2);
    }
    const float pre = xv + wg * acc2;
    float s = pre;
#pragma unroll
    for (int m = 32; m >= 1; m >>= 1) s += __shfl_xor(s, m);
    const float mu = s * (1.0f / 64.0f);
    const float dd = pre - mu;
    float s2 = dd * dd;
#pragma unroll
    for (int m = 32; m >= 1; m >>= 1) s2 += __shfl_xor(s2, m);
    const float inv = rsqrtf(s2 * (1.0f / 64.0f) + LN_EPS);
    const float wln = dd * inv * ng[lane] + nbe[lane];
    float mx = wln;
#pragma unroll
    for (int m = 32; m >= 1; m >>= 1) mx = fmaxf(mx, __shfl_xor(mx, m));
    const float e = __expf(wln - mx);
    float se = e;
#pragma unroll
    for (int m = 32; m >= 1; m >>= 1) se += __shfl_xor(se, m);
    wout_buf[(size_t)tok * NV + lane] = e / se;
}

__device__ __forceinline__ const float* row_ptr(int r, const float* W1, const float* b1,
                                                const float* Wg, const float* bg,
                                                const float* Ws, const float* bs,
                                                const float* b2, const float* g1,
                                                const float* be1) {
    switch (r) {
        case 0: return W1; case 1: return b1; case 2: return Wg; case 3: return bg;
        case 4: return Ws; case 5: return bs; case 6: return b2; case 7: return g1;
        default: return be1;
    }
}

// ---------------- Kernel C: r4 structure + 3-buf counted-vmcnt pipeline ----------
// grid 512 (bid&7 = vgroup/XCD; bid>>3 = 64-token tile). 256 thr = 4 waves; each
// wave = 16 tokens x ALL 256 cols. Hot loop has ZERO compiler global loads (A
// params + x + w LDS-resident), so per-phase sync is exactly:
//   s_waitcnt vmcnt(4); s_barrier      (raw barrier, NO vmcnt(0) drain)
// B panels staged 2 phases ahead into a 3-buffer ring via global_load_lds;
// param rows for var v+1 staged at ks==6 (before the last stage batch, so
// vmcnt(4) covers them). Epilogue is wave-local (no barrier).
__global__ __launch_bounds__(256, 2) void k_main(
    const float* __restrict__ x, const unsigned short* __restrict__ W2T,
    const float* __restrict__ W1, const float* __restrict__ b1,
    const float* __restrict__ Wg, const float* __restrict__ bg,
    const float* __restrict__ Ws, const float* __restrict__ bs,
    const float* __restrict__ b2, const float* __restrict__ g1,
    const float* __restrict__ be1, const float* __restrict__ wgts,
    float* __restrict__ partials,   // [8][NTOK][NH] or nullptr
    float* __restrict__ outacc) {   // atomic fallback
    __shared__ u32x4 sB[3][1024];     // 3 x 16KB B K-step panel ring, slot-swizzled
    __shared__ float sRB[2][9][256];  // 2 x {W1,b1,Wg,bg,Ws,bs,b2,g1,be1}
    __shared__ float sX[64][9];       // [tok][var] (+pad)
    __shared__ float sW[64][9];

    const int tid  = threadIdx.x;
    const int wid  = tid >> 6, lane = tid & 63;  // wid = token-group
    const int c    = lane & 15, kg = lane >> 4;
    const int bid  = blockIdx.x;
    const int vg   = bid & 7, tt = bid >> 3;
    const int t0   = tt * 64, vbase = vg * 8;

    const float* r0p = row_ptr(2 * wid,     W1, b1, Wg, bg, Ws, bs, b2, g1, be1);
    const float* r1p = row_ptr(2 * wid + 1, W1, b1, Wg, bg, Ws, bs, b2, g1, be1);

    // per-thread B-stage constants (4 chunks): idx -> (o, slot) -> src/dst offsets
    int bsrc[4], bdst[4];
#pragma unroll
    for (int q = 0; q < 4; ++q) {
        const int idx = wid * 256 + q * 64 + lane;
        const int o = idx >> 2, sl = idx & 3;
        const int s = (sl - (o >> 1)) & 3;
        bsrc[q] = o * NH + s * 8;   // element offset within the var's W2T
        bdst[q] = idx * 16;         // byte offset within panel
    }

#define STAGE_B(vt, kt, buf)                                                     \
    do {                                                                         \
        const unsigned short* Wsrc_ = W2T + (size_t)(vt) * (NH * NH) + (kt) * 32;\
        char* dst_ = (char*)sB[buf];                                             \
        gload16(Wsrc_ + bsrc[0], dst_ + bdst[0]);                                \
        gload16(Wsrc_ + bsrc[1], dst_ + bdst[1]);                                \
        gload16(Wsrc_ + bsrc[2], dst_ + bdst[2]);                                \
        gload16(Wsrc_ + bsrc[3], dst_ + bdst[3]);                                \
    } while (0)

#define STAGE_ROWS(vt, rbuf)                                                     \
    do {                                                                         \
        gload16(r0p + (size_t)(vt) * NH + lane * 4,                              \
                (char*)sRB[rbuf] + (2 * wid) * 1024);                            \
        gload16(r1p + (size_t)(vt) * NH + lane * 4,                              \
                (char*)sRB[rbuf] + (2 * wid + 1) * 1024);                        \
        if (wid == 0)                                                            \
            gload16(be1 + (size_t)(vt) * NH + lane * 4,                          \
                    (char*)sRB[rbuf] + 8 * 1024);                                \
    } while (0)

    // ---- prologue: stage (v0,ks0)->sB0, (v0,ks1)->sB1, rows v0; fill sX/sW ----
    STAGE_B(vbase, 0, 0);
    STAGE_B(vbase, 1, 1);
    STAGE_ROWS(vbase, 0);
#pragma unroll
    for (int e = 0; e < 2; ++e) {
        const int ee = tid + e * 256;
        const int row = ee >> 3, cc = ee & 7;
        sX[row][cc] = x[(size_t)(t0 + row) * NV + vbase + cc];
        sW[row][cc] = wgts[(size_t)(t0 + row) * NV + vbase + cc];
    }
    __syncthreads();   // one full drain (prologue only)

    // b128 B-frag read base: row o = f*16+c, slot rotated -> balanced banks
    const int rdbase = c * 64 + (((kg + (c >> 1)) & 3) << 4);
    const f32x4 fzero = {0.f, 0.f, 0.f, 0.f};

    f32x4 wacc[16];
#pragma unroll
    for (int f = 0; f < 16; ++f) wacc[f] = fzero;

    int cur = 0;   // sB ring position for the phase being consumed

#pragma unroll 1
    for (int vi = 0; vi < 8; ++vi) {
        const int rcur = vi & 1;
        const float xv = sX[wid * 16 + c][vi];

        f32x4 acc[16];
#pragma unroll
        for (int f = 0; f < 16; ++f) acc[f] = fzero;

#pragma unroll 1
        for (int ks = 0; ks < 8; ++ks) {
            // ---- phase top: counted wait + raw barrier (no vmcnt(0) drain) ----
            asm volatile("s_waitcnt vmcnt(4)" ::: "memory");
            __builtin_amdgcn_sched_barrier(0);
            __builtin_amdgcn_s_barrier();

            // -- A-frag gen (one 16x32 tile per wave) from LDS-resident params --
            const int k0 = ks * 32 + kg * 8;
            const float4 wA = *(const float4*)&sRB[rcur][0][k0];
            const float4 wB = *(const float4*)&sRB[rcur][0][k0 + 4];
            const float4 bA = *(const float4*)&sRB[rcur][1][k0];
            const float4 bB = *(const float4*)&sRB[rcur][1][k0 + 4];
            u32x4 ap;
            {
                const float z0 = fmaf(xv, wA.x, bA.x), z1 = fmaf(xv, wA.y, bA.y);
                const float z2 = fmaf(xv, wA.z, bA.z), z3 = fmaf(xv, wA.w, bA.w);
                const float z4 = fmaf(xv, wB.x, bB.x), z5 = fmaf(xv, wB.y, bB.y);
                const float z6 = fmaf(xv, wB.z, bB.z), z7 = fmaf(xv, wB.w, bB.w);
                ap[0] = pack_bf16x2(felu(z0), felu(z1));
                ap[1] = pack_bf16x2(felu(z2), felu(z3));
                ap[2] = pack_bf16x2(felu(z4), felu(z5));
                ap[3] = pack_bf16x2(felu(z6), felu(z7));
            }

            // -- issue stage for phase p+2 into ring slot (cur+2)%3 --
            {
                const int nxt2 = (cur == 0) ? 2 : cur - 1;   // (cur+2)%3
                if (ks < 6) {
                    STAGE_B(vbase + vi, ks + 2, nxt2);
                } else if (vi < 7) {
                    STAGE_B(vbase + vi + 1, ks - 6, nxt2);
                    if (ks == 6) STAGE_ROWS(vbase + vi + 1, rcur ^ 1);
                }
            }

            // -- MFMA: 16 col-frags, B read in-loop from sB[cur] --
            const short8 af = __builtin_bit_cast(short8, ap);
            const char* bb = (const char*)sB[cur] + rdbase;
            __builtin_amdgcn_s_setprio(1);
#pragma unroll
            for (int f = 0; f < 16; ++f) {
                const short8 bf = __builtin_bit_cast(short8, *(const u32x4*)(bb + (f << 10)));
                acc[f] = __builtin_amdgcn_mfma_f32_16x16x32_bf16(af, bf, acc[f], 0, 0, 0);
            }
            __builtin_amdgcn_s_setprio(0);
            cur = (cur == 2) ? 0 : cur + 1;
        }

        // -- epilogue: gate/skip/sigmoid + wave-local LN + weighted accumulate --
        float xr[4], wv_[4];
#pragma unroll
        for (int r = 0; r < 4; ++r) {
            const int tl = wid * 16 + kg * 4 + r;
            xr[r]  = sX[tl][vi];
            wv_[r] = sW[tl][vi];
        }
        float ps[4] = {}, pq[4] = {};
        float gv[16], bev[16];
#pragma unroll
        for (int f = 0; f < 16; ++f) {
            const int h = f * 16 + c;
            const float Wg_ = sRB[rcur][2][h], bg_ = sRB[rcur][3][h];
            const float Ws_ = sRB[rcur][4][h], bs_ = sRB[rcur][5][h];
            const float b2_ = sRB[rcur][6][h];
            gv[f] = sRB[rcur][7][h]; bev[f] = sRB[rcur][8][h];
#pragma unroll
            for (int r = 0; r < 4; ++r) {
                const float y = fmaf(xr[r], Ws_, bs_) +
                                fsigmoid(fmaf(xr[r], Wg_, bg_)) * (acc[f][r] + b2_);
                acc[f][r] = y;
                ps[r] += y;
                pq[r] = fmaf(y, y, pq[r]);
            }
        }
#pragma unroll
        for (int m = 1; m <= 8; m <<= 1)
#pragma unroll
            for (int r = 0; r < 4; ++r) {
                ps[r] += __shfl_xor(ps[r], m);
                pq[r] += __shfl_xor(pq[r], m);
            }
#pragma unroll
        for (int r = 0; r < 4; ++r) {
            const float mu = ps[r] * (1.0f / 256.0f);
            const float vr = fmaf(-mu, mu, pq[r] * (1.0f / 256.0f));
            const float iv = rsqrtf(vr + LN_EPS);
            const float wiv = wv_[r] * iv;
#pragma unroll
            for (int f = 0; f < 16; ++f)
                wacc[f][r] = fmaf(wiv * (acc[f][r] - mu), gv[f],
                                  fmaf(wv_[r], bev[f], wacc[f][r]));
        }
    }
#undef STAGE_B
#undef STAGE_ROWS

    // -- write per-vgroup partials --
    const int tokb = t0 + wid * 16 + kg * 4;
    if (partials) {
        float* P = partials + (size_t)vg * NTOK * NH;
#pragma unroll
        for (int r = 0; r < 4; ++r) {
            float* rowp = P + (size_t)(tokb + r) * NH + c;
#pragma unroll
            for (int f = 0; f < 16; ++f) rowp[f * 16] = wacc[f][r];
        }
    } else {
#pragma unroll
        for (int r = 0; r < 4; ++r) {
            float* rowp = outacc + (size_t)(tokb + r) * NH + c;
#pragma unroll
            for (int f = 0; f < 16; ++f) atomicAdd(&rowp[f * 16], wacc[f][r]);
        }
    }
}

// ---------------- Kernel D: sum the 8 vgroup partials ----------------
__global__ __launch_bounds__(256) void k_reduce(const float* __restrict__ P,
                                                float* __restrict__ out) {
    const size_t i = ((size_t)blockIdx.x * 256 + threadIdx.x);
    const f32x4* P4 = (const f32x4*)P;
    f32x4 s = P4[i];
#pragma unroll
    for (int sl = 1; sl < 8; ++sl) s += P4[(size_t)sl * (NTOK * NH / 4) + i];
    ((f32x4*)out)[i] = s;
}

extern "C" void kernel_launch(void* const* d_in, const int* in_sizes, int n_in,
                              void* d_out, int out_size, void* d_ws, size_t ws_size,
                              hipStream_t stream) {
    const float* x   = (const float*)d_in[0];
    const float* W1  = (const float*)d_in[1];
    const float* b1  = (const float*)d_in[2];
    const float* W2  = (const float*)d_in[3];
    const float* b2  = (const float*)d_in[4];
    const float* Wg  = (const float*)d_in[5];
    const float* bg  = (const float*)d_in[6];
    const float* Ws  = (const float*)d_in[7];
    const float* bs  = (const float*)d_in[8];
    const float* g1  = (const float*)d_in[9];
    const float* be1 = (const float*)d_in[10];
    const float* nW1 = (const float*)d_in[11];
    const float* nb1 = (const float*)d_in[12];
    const float* nW2 = (const float*)d_in[13];
    const float* nb2 = (const float*)d_in[14];
    const float* nWg = (const float*)d_in[15];
    const float* nbg = (const float*)d_in[16];
    const float* ng  = (const float*)d_in[17];
    const float* nbe = (const float*)d_in[18];
    float* out = (float*)d_out;

    // ws layout: [0,1MB) weights | [1MB,9MB) W2T bf16 | [9MB,41MB) partials
    char* ws = (char*)d_ws;
    float* ws_wgt = (float*)ws;
    unsigned short* ws_W2T = (unsigned short*)(ws + (1 << 20));
    const size_t part_off = (size_t)9 << 20;
    const size_t part_bytes = (size_t)8 * NTOK * NH * 4;
    const bool use_part = ws_size >= part_off + part_bytes;
    float* ws_part = use_part ? (float*)(ws + part_off) : nullptr;

    k_w2t<<<dim3(64 * 64), dim3(256), 0, stream>>>(W2, ws_W2T);
    k_weights<<<dim3(NTOK / 4), dim3(256), 0, stream>>>(x, nW1, nb1, nW2, nb2,
                                                        nWg, nbg, ng, nbe, ws_wgt);
    if (!use_part) hipMemsetAsync(d_out, 0, (size_t)out_size * 4, stream);
    k_main<<<dim3(512), dim3(256), 0, stream>>>(x, ws_W2T, W1, b1, Wg, bg, Ws, bs,
                                                b2, g1, be1, ws_wgt, ws_part, out);
    if (use_part)
        k_reduce<<<dim3(NTOK * NH / 4 / 256), dim3(256), 0, stream>>>(ws_part, out);
}

// Round 11
// 128.787 us; speedup vs baseline: 3.3677x; 1.0971x over previous
//
#include <hip/hip_runtime.h>
#include <hip/hip_bf16.h>
#include <stdint.h>

// VSN: B=16,T=256 -> NTOK=4096 tokens, V=64 vars, H=256 hidden.
#define NTOK 4096
#define NV 64
#define NH 256
#define LN_EPS 1e-5f

typedef __attribute__((ext_vector_type(8))) short short8;
typedef __attribute__((ext_vector_type(4))) float f32x4;
typedef __attribute__((ext_vector_type(2))) float f32x2;   // true vector: safe in asm "v"
typedef __attribute__((ext_vector_type(4))) uint32_t u32x4;

__device__ __forceinline__ f32x2 mk2(float a, float b) {
    f32x2 r; r.x = a; r.y = b; return r;
}
__device__ __forceinline__ unsigned short f32_to_bf16(float f) {
    uint32_t u = __builtin_bit_cast(uint32_t, f);
    return (unsigned short)((u + 0x7FFFu + ((u >> 16) & 1u)) >> 16);  // RNE
}
__device__ __forceinline__ float fsigmoid(float z) { return 1.0f / (1.0f + __expf(-z)); }
__device__ __forceinline__ float felu(float z) { return z > 0.0f ? z : (__expf(z) - 1.0f); }
// packed f32 dual-rate math (VOP3P, CDNA3+) on genuine ext-vector pairs
__device__ __forceinline__ f32x2 pk_fma(f32x2 a, f32x2 b, f32x2 c) {
    f32x2 d;
    asm("v_pk_fma_f32 %0, %1, %2, %3" : "=v"(d) : "v"(a), "v"(b), "v"(c));
    return d;
}
__device__ __forceinline__ f32x2 pk_add(f32x2 a, f32x2 b) {
    f32x2 d;
    asm("v_pk_add_f32 %0, %1, %2" : "=v"(d) : "v"(a), "v"(b));
    return d;
}
__device__ __forceinline__ f32x2 pk_mul(f32x2 a, f32x2 b) {
    f32x2 d;
    asm("v_pk_mul_f32 %0, %1, %2" : "=v"(d) : "v"(a), "v"(b));
    return d;
}
__device__ __forceinline__ uint32_t cvtpk_bf16(float lo, float hi) {
    uint32_t r;
    asm("v_cvt_pk_bf16_f32 %0, %1, %2" : "=v"(r) : "v"(lo), "v"(hi));
    return r;
}
__device__ __forceinline__ void gload16(const void* g, void* l) {
    __builtin_amdgcn_global_load_lds(
        (const __attribute__((address_space(1))) uint32_t*)g,
        (__attribute__((address_space(3))) uint32_t*)l, 16, 0, 0);
}

// ---------------- Kernel A: W2 [v][h][o] f32 -> W2T [v][o][h] bf16 ----------------
__global__ __launch_bounds__(256) void k_w2t(const float* __restrict__ W2,
                                             unsigned short* __restrict__ W2T) {
    __shared__ float tile[32][33];
    const int v  = blockIdx.x >> 6;
    const int t  = blockIdx.x & 63;
    const int h0 = (t & 7) * 32;
    const int o0 = (t >> 3) * 32;
    const int r  = threadIdx.x >> 3;
    const int c4 = (threadIdx.x & 7) * 4;
    const float4 d = *(const float4*)(W2 + ((size_t)v * NH + h0 + r) * NH + o0 + c4);
    tile[r][c4 + 0] = d.x; tile[r][c4 + 1] = d.y;
    tile[r][c4 + 2] = d.z; tile[r][c4 + 3] = d.w;
    __syncthreads();
    ushort4 o;
    o.x = f32_to_bf16(tile[c4 + 0][r]);
    o.y = f32_to_bf16(tile[c4 + 1][r]);
    o.z = f32_to_bf16(tile[c4 + 2][r]);
    o.w = f32_to_bf16(tile[c4 + 3][r]);
    *(ushort4*)(W2T + ((size_t)v * NH + o0 + r) * NH + h0 + c4) = o;
}

// ---------------- Kernel A3: scale Wg,bg by -log2(e) for exp2-native sigmoid ------
__global__ __launch_bounds__(256) void k_scale(const float* __restrict__ Wg,
                                               const float* __restrict__ bg,
                                               float* __restrict__ Wg2,
                                               float* __restrict__ bg2) {
    const int i = blockIdx.x * 256 + threadIdx.x;   // 4096 float4s
    const float c = -1.44269504f;
    const float4 a = ((const float4*)Wg)[i];
    const float4 b = ((const float4*)bg)[i];
    ((float4*)Wg2)[i] = float4{a.x * c, a.y * c, a.z * c, a.w * c};
    ((float4*)bg2)[i] = float4{b.x * c, b.y * c, b.z * c, b.w * c};
}

// ---------------- Kernel B: weight-network GRN + softmax -> weights[tok][v] -------
__global__ __launch_bounds__(256) void k_weights(
    const float* __restrict__ x,
    const float* __restrict__ nW1, const float* __restrict__ nb1,
    const float* __restrict__ nW2, const float* __restrict__ nb2,
    const float* __restrict__ nWg, const float* __restrict__ nbg,
    const float* __restrict__ ng,  const float* __restrict__ nbe,
    float* __restrict__ wout_buf) {
    const int wv = threadIdx.x >> 6;
    const int lane = threadIdx.x & 63;
    const int tok = blockIdx.x * 4 + wv;
    const float xv = x[(size_t)tok * NV + lane];
    float acc1 = nb1[lane], accg = nbg[lane];
#pragma unroll 8
    for (int k = 0; k < 64; ++k) {
        const float xk = __shfl(xv, k);
        acc1 = fmaf(xk, nW1[k * 64 + lane], acc1);
        accg = fmaf(xk, nWg[k * 64 + lane], accg);
    }
    const float h  = felu(acc1);
    const float wg = fsigmoid(accg);
    float acc2 = nb2[lane];
#pragma unroll 8
    for (int k = 0; k < 64; ++k) {
        const float hk = __shfl(h, k);
        acc2 = fmaf(hk, nW2[k * 64 + lane], acc2);
    }
    const float pre = xv + wg * acc2;
    float s = pre;
#pragma unroll
    for (int m = 32; m >= 1; m >>= 1) s += __shfl_xor(s, m);
    const float mu = s * (1.0f / 64.0f);
    const float dd = pre - mu;
    float s2 = dd * dd;
#pragma unroll
    for (int m = 32; m >= 1; m >>= 1) s2 += __shfl_xor(s2, m);
    const float inv = rsqrtf(s2 * (1.0f / 64.0f) + LN_EPS);
    const float wln = dd * inv * ng[lane] + nbe[lane];
    float mx = wln;
#pragma unroll
    for (int m = 32; m >= 1; m >>= 1) mx = fmaxf(mx, __shfl_xor(mx, m));
    const float e = __expf(wln - mx);
    float se = e;
#pragma unroll
    for (int m = 32; m >= 1; m >>= 1) se += __shfl_xor(se, m);
    wout_buf[(size_t)tok * NV + lane] = e / se;
}

__device__ __forceinline__ const float* row_ptr(int r, const float* W1, const float* b1,
                                                const float* Wg, const float* bg,
                                                const float* Ws, const float* bs,
                                                const float* b2, const float* g1,
                                                const float* be1) {
    switch (r) {
        case 0: return W1; case 1: return b1; case 2: return Wg; case 3: return bg;
        case 4: return Ws; case 5: return bs; case 6: return b2; case 7: return g1;
        default: return be1;
    }
}

// ---------------- Kernel C: r9 pipeline + packed-f32 arithmetic (fixed types) -----
// grid 512 (bid&7 = vgroup/XCD; bid>>3 = 64-token tile). 256 thr = 4 waves; each
// wave = 16 tokens x ALL 256 cols. Per-phase sync: s_waitcnt vmcnt(4) + raw
// s_barrier (3-buf B ring staged 2 phases ahead). Arithmetic: v_pk_* on f32x2
// ext-vectors, exp2-native sigmoid (pre-scaled Wg2/bg2), v_cvt_pk_bf16 A-pack.
__global__ __launch_bounds__(256, 2) void k_main(
    const float* __restrict__ x, const unsigned short* __restrict__ W2T,
    const float* __restrict__ W1, const float* __restrict__ b1,
    const float* __restrict__ Wg2, const float* __restrict__ bg2,
    const float* __restrict__ Ws, const float* __restrict__ bs,
    const float* __restrict__ b2, const float* __restrict__ g1,
    const float* __restrict__ be1, const float* __restrict__ wgts,
    float* __restrict__ partials,   // [8][NTOK][NH] or nullptr
    float* __restrict__ outacc) {   // atomic fallback
    __shared__ u32x4 sB[3][1024];     // 3 x 16KB B K-step panel ring, slot-swizzled
    __shared__ float sRB[2][9][256];  // 2 x {W1,b1,Wg2,bg2,Ws,bs,b2,g1,be1}
    __shared__ float sX[64][9];       // [tok][var] (+pad)
    __shared__ float sW[64][9];

    const int tid  = threadIdx.x;
    const int wid  = tid >> 6, lane = tid & 63;  // wid = token-group
    const int c    = lane & 15, kg = lane >> 4;
    const int bid  = blockIdx.x;
    const int vg   = bid & 7, tt = bid >> 3;
    const int t0   = tt * 64, vbase = vg * 8;

    const float* r0p = row_ptr(2 * wid,     W1, b1, Wg2, bg2, Ws, bs, b2, g1, be1);
    const float* r1p = row_ptr(2 * wid + 1, W1, b1, Wg2, bg2, Ws, bs, b2, g1, be1);

    // per-thread B-stage constants (4 chunks): idx -> (o, slot) -> src/dst offsets
    int bsrc[4], bdst[4];
#pragma unroll
    for (int q = 0; q < 4; ++q) {
        const int idx = wid * 256 + q * 64 + lane;
        const int o = idx >> 2, sl = idx & 3;
        const int s = (sl - (o >> 1)) & 3;
        bsrc[q] = o * NH + s * 8;   // element offset within the var's W2T
        bdst[q] = idx * 16;         // byte offset within panel
    }

#define STAGE_B(vt, kt, buf)                                                     \
    do {                                                                         \
        const unsigned short* Wsrc_ = W2T + (size_t)(vt) * (NH * NH) + (kt) * 32;\
        char* dst_ = (char*)sB[buf];                                             \
        gload16(Wsrc_ + bsrc[0], dst_ + bdst[0]);                                \
        gload16(Wsrc_ + bsrc[1], dst_ + bdst[1]);                                \
        gload16(Wsrc_ + bsrc[2], dst_ + bdst[2]);                                \
        gload16(Wsrc_ + bsrc[3], dst_ + bdst[3]);                                \
    } while (0)

#define STAGE_ROWS(vt, rbuf)                                                     \
    do {                                                                         \
        gload16(r0p + (size_t)(vt) * NH + lane * 4,                              \
                (char*)sRB[rbuf] + (2 * wid) * 1024);                            \
        gload16(r1p + (size_t)(vt) * NH + lane * 4,                              \
                (char*)sRB[rbuf] + (2 * wid + 1) * 1024);                        \
        if (wid == 0)                                                            \
            gload16(be1 + (size_t)(vt) * NH + lane * 4,                          \
                    (char*)sRB[rbuf] + 8 * 1024);                                \
    } while (0)

    // ---- prologue: stage (v0,ks0)->sB0, (v0,ks1)->sB1, rows v0; fill sX/sW ----
    STAGE_B(vbase, 0, 0);
    STAGE_B(vbase, 1, 1);
    STAGE_ROWS(vbase, 0);
#pragma unroll
    for (int e = 0; e < 2; ++e) {
        const int ee = tid + e * 256;
        const int row = ee >> 3, cc = ee & 7;
        sX[row][cc] = x[(size_t)(t0 + row) * NV + vbase + cc];
        sW[row][cc] = wgts[(size_t)(t0 + row) * NV + vbase + cc];
    }
    __syncthreads();   // one full drain (prologue only)

    // b128 B-frag read base: row o = f*16+c, slot rotated -> balanced banks
    const int rdbase = c * 64 + (((kg + (c >> 1)) & 3) << 4);
    const f32x4 fzero = {0.f, 0.f, 0.f, 0.f};
    const f32x2 one2 = {1.0f, 1.0f};

    f32x4 wacc[16];
#pragma unroll
    for (int f = 0; f < 16; ++f) wacc[f] = fzero;

    int cur = 0;   // sB ring position for the phase being consumed

#pragma unroll 1
    for (int vi = 0; vi < 8; ++vi) {
        const int rcur = vi & 1;
        const float xv = sX[wid * 16 + c][vi];
        const f32x2 xv2 = {xv, xv};

        f32x4 acc[16];
#pragma unroll
        for (int f = 0; f < 16; ++f) acc[f] = fzero;

#pragma unroll 1
        for (int ks = 0; ks < 8; ++ks) {
            // ---- phase top: counted wait + raw barrier (no vmcnt(0) drain) ----
            asm volatile("s_waitcnt vmcnt(4)" ::: "memory");
            __builtin_amdgcn_sched_barrier(0);
            __builtin_amdgcn_s_barrier();

            // -- A-frag gen (one 16x32 tile per wave): pk-fma pairs + cvt_pk --
            const int k0 = ks * 32 + kg * 8;
            const float4 wA = *(const float4*)&sRB[rcur][0][k0];
            const float4 wB = *(const float4*)&sRB[rcur][0][k0 + 4];
            const float4 bA = *(const float4*)&sRB[rcur][1][k0];
            const float4 bB = *(const float4*)&sRB[rcur][1][k0 + 4];
            u32x4 ap;
            {
                const f32x2 z0 = pk_fma(xv2, mk2(wA.x, wA.y), mk2(bA.x, bA.y));
                const f32x2 z1 = pk_fma(xv2, mk2(wA.z, wA.w), mk2(bA.z, bA.w));
                const f32x2 z2 = pk_fma(xv2, mk2(wB.x, wB.y), mk2(bB.x, bB.y));
                const f32x2 z3 = pk_fma(xv2, mk2(wB.z, wB.w), mk2(bB.z, bB.w));
                ap[0] = cvtpk_bf16(felu(z0.x), felu(z0.y));
                ap[1] = cvtpk_bf16(felu(z1.x), felu(z1.y));
                ap[2] = cvtpk_bf16(felu(z2.x), felu(z2.y));
                ap[3] = cvtpk_bf16(felu(z3.x), felu(z3.y));
            }

            // -- issue stage for phase p+2 into ring slot (cur+2)%3 --
            {
                const int nxt2 = (cur == 0) ? 2 : cur - 1;   // (cur+2)%3
                if (ks < 6) {
                    STAGE_B(vbase + vi, ks + 2, nxt2);
                } else if (vi < 7) {
                    STAGE_B(vbase + vi + 1, ks - 6, nxt2);
                    if (ks == 6) STAGE_ROWS(vbase + vi + 1, rcur ^ 1);
                }
            }

            // -- MFMA: 16 col-frags, B read in-loop from sB[cur] --
            const short8 af = __builtin_bit_cast(short8, ap);
            const char* bb = (const char*)sB[cur] + rdbase;
            __builtin_amdgcn_s_setprio(1);
#pragma unroll
            for (int f = 0; f < 16; ++f) {
                const short8 bf = __builtin_bit_cast(short8, *(const u32x4*)(bb + (f << 10)));
                acc[f] = __builtin_amdgcn_mfma_f32_16x16x32_bf16(af, bf, acc[f], 0, 0, 0);
            }
            __builtin_amdgcn_s_setprio(0);
            cur = (cur == 2) ? 0 : cur + 1;
        }

        // -- epilogue (pk-f32 pairs): gate/skip + wave-local LN + weighted acc --
        float xr[4], wv_[4];
#pragma unroll
        for (int r = 0; r < 4; ++r) {
            const int tl = wid * 16 + kg * 4 + r;
            xr[r]  = sX[tl][vi];
            wv_[r] = sW[tl][vi];
        }
        const f32x2 xr01 = {xr[0], xr[1]}, xr23 = {xr[2], xr[3]};
        f32x2 ps01 = {0.f, 0.f}, ps23 = {0.f, 0.f};
        f32x2 pq01 = {0.f, 0.f}, pq23 = {0.f, 0.f};
#pragma unroll
        for (int f = 0; f < 16; ++f) {
            const int h = f * 16 + c;
            const float Wg_ = sRB[rcur][2][h], bg_ = sRB[rcur][3][h];  // pre-scaled
            const float Ws_ = sRB[rcur][4][h], bs_ = sRB[rcur][5][h];
            const float b2_ = sRB[rcur][6][h];
            const f32x2 Wgp = {Wg_, Wg_}, bgp = {bg_, bg_};
            const f32x2 Wsp = {Ws_, Ws_}, bsp = {bs_, bs_}, b2p = {b2_, b2_};
            const f32x2 a01 = {acc[f][0], acc[f][1]};
            const f32x2 a23 = {acc[f][2], acc[f][3]};
            const f32x2 zg01 = pk_fma(xr01, Wgp, bgp);
            const f32x2 zg23 = pk_fma(xr23, Wgp, bgp);
            const f32x2 e01 = {exp2f(zg01.x), exp2f(zg01.y)};
            const f32x2 e23 = {exp2f(zg23.x), exp2f(zg23.y)};
            const f32x2 d01 = pk_add(e01, one2);
            const f32x2 d23 = pk_add(e23, one2);
            const f32x2 s01 = {__builtin_amdgcn_rcpf(d01.x), __builtin_amdgcn_rcpf(d01.y)};
            const f32x2 s23 = {__builtin_amdgcn_rcpf(d23.x), __builtin_amdgcn_rcpf(d23.y)};
            const f32x2 R01 = pk_add(a01, b2p);
            const f32x2 R23 = pk_add(a23, b2p);
            const f32x2 sk01 = pk_fma(xr01, Wsp, bsp);
            const f32x2 sk23 = pk_fma(xr23, Wsp, bsp);
            const f32x2 y01 = pk_fma(s01, R01, sk01);
            const f32x2 y23 = pk_fma(s23, R23, sk23);
            ps01 = pk_add(ps01, y01);
            ps23 = pk_add(ps23, y23);
            pq01 = pk_fma(y01, y01, pq01);
            pq23 = pk_fma(y23, y23, pq23);
            acc[f][0] = y01.x; acc[f][1] = y01.y;
            acc[f][2] = y23.x; acc[f][3] = y23.y;
        }
        float ps[4] = {ps01.x, ps01.y, ps23.x, ps23.y};
        float pq[4] = {pq01.x, pq01.y, pq23.x, pq23.y};
#pragma unroll
        for (int m = 1; m <= 8; m <<= 1)
#pragma unroll
            for (int r = 0; r < 4; ++r) {
                ps[r] += __shfl_xor(ps[r], m);
                pq[r] += __shfl_xor(pq[r], m);
            }
        float nmu[4], wiv[4];
#pragma unroll
        for (int r = 0; r < 4; ++r) {
            const float mu = ps[r] * (1.0f / 256.0f);
            const float vr = fmaf(-mu, mu, pq[r] * (1.0f / 256.0f));
            nmu[r] = -mu;
            wiv[r] = wv_[r] * rsqrtf(vr + LN_EPS);
        }
        const f32x2 nmu01 = {nmu[0], nmu[1]}, nmu23 = {nmu[2], nmu[3]};
        const f32x2 wiv01 = {wiv[0], wiv[1]}, wiv23 = {wiv[2], wiv[3]};
        const f32x2 wv01 = {wv_[0], wv_[1]}, wv23 = {wv_[2], wv_[3]};
#pragma unroll
        for (int f = 0; f < 16; ++f) {
            const int h = f * 16 + c;
            const float gv_ = sRB[rcur][7][h], bev_ = sRB[rcur][8][h];
            const f32x2 gvp = {gv_, gv_}, bevp = {bev_, bev_};
            f32x2 w01 = {wacc[f][0], wacc[f][1]};
            f32x2 w23 = {wacc[f][2], wacc[f][3]};
            const f32x2 y01 = {acc[f][0], acc[f][1]};
            const f32x2 y23 = {acc[f][2], acc[f][3]};
            const f32x2 t01 = pk_mul(pk_add(y01, nmu01), wiv01);
            const f32x2 t23 = pk_mul(pk_add(y23, nmu23), wiv23);
            w01 = pk_fma(t01, gvp, pk_fma(wv01, bevp, w01));
            w23 = pk_fma(t23, gvp, pk_fma(wv23, bevp, w23));
            wacc[f][0] = w01.x; wacc[f][1] = w01.y;
            wacc[f][2] = w23.x; wacc[f][3] = w23.y;
        }
    }
#undef STAGE_B
#undef STAGE_ROWS

    // -- write per-vgroup partials --
    const int tokb = t0 + wid * 16 + kg * 4;
    if (partials) {
        float* P = partials + (size_t)vg * NTOK * NH;
#pragma unroll
        for (int r = 0; r < 4; ++r) {
            float* rowp = P + (size_t)(tokb + r) * NH + c;
#pragma unroll
            for (int f = 0; f < 16; ++f) rowp[f * 16] = wacc[f][r];
        }
    } else {
#pragma unroll
        for (int r = 0; r < 4; ++r) {
            float* rowp = outacc + (size_t)(tokb + r) * NH + c;
#pragma unroll
            for (int f = 0; f < 16; ++f) atomicAdd(&rowp[f * 16], wacc[f][r]);
        }
    }
}

// ---------------- Kernel D: sum the 8 vgroup partials ----------------
__global__ __launch_bounds__(256) void k_reduce(const float* __restrict__ P,
                                                float* __restrict__ out) {
    const size_t i = ((size_t)blockIdx.x * 256 + threadIdx.x);
    const f32x4* P4 = (const f32x4*)P;
    f32x4 s = P4[i];
#pragma unroll
    for (int sl = 1; sl < 8; ++sl) s += P4[(size_t)sl * (NTOK * NH / 4) + i];
    ((f32x4*)out)[i] = s;
}

extern "C" void kernel_launch(void* const* d_in, const int* in_sizes, int n_in,
                              void* d_out, int out_size, void* d_ws, size_t ws_size,
                              hipStream_t stream) {
    const float* x   = (const float*)d_in[0];
    const float* W1  = (const float*)d_in[1];
    const float* b1  = (const float*)d_in[2];
    const float* W2  = (const float*)d_in[3];
    const float* b2  = (const float*)d_in[4];
    const float* Wg  = (const float*)d_in[5];
    const float* bg  = (const float*)d_in[6];
    const float* Ws  = (const float*)d_in[7];
    const float* bs  = (const float*)d_in[8];
    const float* g1  = (const float*)d_in[9];
    const float* be1 = (const float*)d_in[10];
    const float* nW1 = (const float*)d_in[11];
    const float* nb1 = (const float*)d_in[12];
    const float* nW2 = (const float*)d_in[13];
    const float* nb2 = (const float*)d_in[14];
    const float* nWg = (const float*)d_in[15];
    const float* nbg = (const float*)d_in[16];
    const float* ng  = (const float*)d_in[17];
    const float* nbe = (const float*)d_in[18];
    float* out = (float*)d_out;

    // ws: [0,1M) wgt | [1M,9M) W2T | [9M,+64K) Wg2 | [+64K,+128K) bg2 |
    //     [10M,42M) partials
    char* ws = (char*)d_ws;
    float* ws_wgt = (float*)ws;
    unsigned short* ws_W2T = (unsigned short*)(ws + (1 << 20));
    float* ws_Wg2 = (float*)(ws + (9 << 20));
    float* ws_bg2 = (float*)(ws + (9 << 20) + (64 << 10));
    const size_t part_off = (size_t)10 << 20;
    const size_t part_bytes = (size_t)8 * NTOK * NH * 4;
    const bool use_part = ws_size >= part_off + part_bytes;
    float* ws_part = use_part ? (float*)(ws + part_off) : nullptr;

    k_w2t<<<dim3(64 * 64), dim3(256), 0, stream>>>(W2, ws_W2T);
    k_scale<<<dim3(16), dim3(256), 0, stream>>>(Wg, bg, ws_Wg2, ws_bg2);
    k_weights<<<dim3(NTOK / 4), dim3(256), 0, stream>>>(x, nW1, nb1, nW2, nb2,
                                                        nWg, nbg, ng, nbe, ws_wgt);
    if (!use_part) hipMemsetAsync(d_out, 0, (size_t)out_size * 4, stream);
    k_main<<<dim3(512), dim3(256), 0, stream>>>(x, ws_W2T, W1, b1, ws_Wg2, ws_bg2,
                                                Ws, bs, b2, g1, be1, ws_wgt,
                                                ws_part, out);
    if (use_part)
        k_reduce<<<dim3(NTOK * NH / 4 / 256), dim3(256), 0, stream>>>(ws_part, out);
}